// Round 1
// baseline (1571.257 us; speedup 1.0000x reference)
//
#include <hip/hip_runtime.h>

typedef _Float16 f16;
typedef _Float16 f16x8 __attribute__((ext_vector_type(8)));
typedef _Float16 f16x4 __attribute__((ext_vector_type(4)));
typedef float f32x4 __attribute__((ext_vector_type(4)));

#define MFMA16(a, b, c) __builtin_amdgcn_mfma_f32_16x16x32_f16((a), (b), (c), 0, 0, 0)

#define OFF_B 46080           // start of region B (xs / z) in bytes
#define SMEM_BYTES (46080 + 17408)

__device__ __forceinline__ float sigm(float v) { return 1.0f / (1.0f + __expf(-v)); }
__device__ __forceinline__ float tanh_(float v) { return 1.0f - 2.0f / (__expf(2.0f * v) + 1.0f); }

// One block = 16 batch samples, 256 threads = 4 waves.
// wave = (mgroup in {0,1}) x (ngroup in {0,1}); mgroup picks channels 0-15 / 16-31
// of each gate; ngroup picks samples 0-7 / 8-15.
// Recurrence GEMM: gates[oc=128][(b,pos)=256] via 9 tap-GEMMs (K=32) + 1 x-GEMM (K=27->32).
// MFMA layouts (m89/m91-verified): A: m=lane&15, k=(lane>>4)*8+j ; B: n=lane&15, same k ;
// D: col=lane&15, row=(lane>>4)*4+reg.
extern "C" __global__ __launch_bounds__(256, 1)
void hwq_fused(const float* __restrict__ gx, const float* __restrict__ ghour,
               const float* __restrict__ gcw, const float* __restrict__ gcb,
               const float* __restrict__ ghw1, const float* __restrict__ ghb1,
               const float* __restrict__ ghw2, const float* __restrict__ ghb2,
               const float* __restrict__ gdw1, const float* __restrict__ gdb1,
               const float* __restrict__ gdw2, const float* __restrict__ gdb2,
               const float* __restrict__ gdw3, const float* __restrict__ gdb3,
               float* __restrict__ gout)
{
  __shared__ __align__(16) char smem[SMEM_BYTES];
  const int tid = threadIdx.x;
  const int lane = tid & 63;
  const int wv = tid >> 6;
  const int mg = wv & 1;      // m-group: channels mg*16 .. mg*16+15 of each gate
  const int ng = wv >> 1;     // n-group: samples ng*8 .. ng*8+7
  const int lr = lane & 15;   // row (A) / col (B,D) lane index
  const int lk = lane >> 4;   // k-group (8 elems each)
  const int bg = blockIdx.x << 4;

  // ---------------- stage conv hidden-state weights -> A-fragments (registers)
  // conv_w layout: [oc 128][icc 35][3][3]; h-part icc = 3+ic -> offset oc*315 + 27 + ic*9 + tap
  f16x8 Ah[9][4];
  {
    f16* wst = (f16*)(smem);  // chunk: [64 oc][288 = ic*9+tap] f16
    #pragma unroll
    for (int c = 0; c < 2; ++c) {
      __syncthreads();
      for (int i = tid; i < 18432; i += 256) {
        int oc = i / 288, rem = i - oc * 288;
        wst[i] = (f16)gcw[(c * 64 + oc) * 315 + 27 + rem];
      }
      __syncthreads();
      #pragma unroll
      for (int g = 0; g < 2; ++g) {    // chunk0 -> gates 0(i),1(f); chunk1 -> 2(o),3(g)
        int ocl = g * 32 + mg * 16 + lr;
        #pragma unroll
        for (int tap = 0; tap < 9; ++tap) {
          f16x8 f;
          #pragma unroll
          for (int j = 0; j < 8; ++j)
            f[j] = wst[ocl * 288 + (lk * 8 + j) * 9 + tap];
          Ah[tap][c * 2 + g] = f;
        }
      }
    }
  }
  // ---------------- x-part weights, K packed as k = tap*3 + ic (27 valid, pad to 32)
  f16x8 Ax[4];
  {
    f16* xw = (f16*)(smem + OFF_B);  // [128 oc][27 = ic*9+tap] f16
    __syncthreads();
    for (int i = tid; i < 3456; i += 256) {
      int oc = i / 27, rem = i - oc * 27;
      xw[i] = (f16)gcw[oc * 315 + rem];   // icc = ic (0..2)
    }
    __syncthreads();
    #pragma unroll
    for (int mt = 0; mt < 4; ++mt) {
      int oc = mt * 32 + mg * 16 + lr;
      f16x8 f;
      #pragma unroll
      for (int j = 0; j < 8; ++j) {
        int k = lk * 8 + j;
        int tap = (k * 11) >> 5;        // floor(k/3) for k < 27
        int ic = k - 3 * tap;
        f16 v = (f16)0.0f;
        if (k < 27) v = xw[oc * 27 + ic * 9 + tap];
        f[j] = v;
      }
      Ax[mt] = f;
    }
    __syncthreads();
  }

  // biases for this lane's 16 (gate, ch) accumulator slots
  float bias[4][4];
  #pragma unroll
  for (int mt = 0; mt < 4; ++mt)
    #pragma unroll
    for (int r = 0; r < 4; ++r)
      bias[mt][r] = gcb[mt * 32 + mg * 16 + lk * 4 + r];

  // ---------------- zero hpad (h0 = 0, borders stay 0) + xs, stage xs(t=0)
  {
    float* za = (float*)smem;
    for (int i = tid; i < 11520; i += 256) za[i] = 0.0f;   // hpad [16][36][40] f16
    float* zb = (float*)(smem + OFF_B);
    for (int i = tid; i < 1152; i += 256) zb[i] = 0.0f;    // xs [16][36][4] f16
    __syncthreads();
    for (int i = tid; i < 768; i += 256) {
      int b = i / 48, rem = i - b * 48;
      int pos = rem & 15;
      int ic = rem >> 4;
      int pp = (pos >> 2) * 6 + (pos & 3) + 7;  // interior of 6x6
      *(f16*)(smem + OFF_B + b * 288 + pp * 8 + ic * 2) =
          (f16)gx[(size_t)(bg + b) * 576 + rem];
    }
    __syncthreads();
  }

  // per-ntile base addresses (byte offsets into smem)
  int hbase[8], xbase[8], wbase[8];
  #pragma unroll
  for (int nt = 0; nt < 8; ++nt) {
    int n = ng * 128 + nt * 16 + lr;
    int b = n >> 4, pos = n & 15;
    int pp0 = (pos >> 2) * 6 + (pos & 3);
    hbase[nt] = b * 2880 + pp0 * 80 + lk * 16;                    // B-frag read base
    xbase[nt] = OFF_B + b * 288 + pp0 * 8;                        // x gather base
    wbase[nt] = b * 2880 + (pp0 + 7) * 80 + (mg * 16 + lk * 4) * 2; // h' write base
  }
  int xoff[8], xval[8];
  #pragma unroll
  for (int j = 0; j < 8; ++j) {
    int k = lk * 8 + j;
    int tap = (k * 11) >> 5;
    int ic = k - 3 * tap;
    xoff[j] = ((tap / 3) * 6 + (tap % 3)) * 8 + ic * 2;
    xval[j] = (k < 27);
  }

  const int TOFF[9] = {0, 1, 2, 6, 7, 8, 12, 13, 14};  // (dy*6+dx) per tap

  f32x4 cst[8];
  #pragma unroll
  for (int nt = 0; nt < 8; ++nt) { f32x4 z = {0.f, 0.f, 0.f, 0.f}; cst[nt] = z; }

  // ================= recurrence =================
  for (int t = 0; t < 12; ++t) {
    f32x4 acc[4][8];
    #pragma unroll
    for (int mt = 0; mt < 4; ++mt) {
      f32x4 bi = {bias[mt][0], bias[mt][1], bias[mt][2], bias[mt][3]};
      #pragma unroll
      for (int nt = 0; nt < 8; ++nt) acc[mt][nt] = bi;
    }
    // h-part: 9 taps x K=32
    #pragma unroll
    for (int tap = 0; tap < 9; ++tap) {
      #pragma unroll
      for (int nt = 0; nt < 8; ++nt) {
        f16x8 bf = *(const f16x8*)(smem + hbase[nt] + TOFF[tap] * 80);
        #pragma unroll
        for (int mt = 0; mt < 4; ++mt)
          acc[mt][nt] = MFMA16(Ah[tap][mt], bf, acc[mt][nt]);
      }
    }
    // x-part: one K=32 MFMA per ntile (27 valid k, rest read the zero border)
    #pragma unroll
    for (int nt = 0; nt < 8; ++nt) {
      f16x8 bf;
      #pragma unroll
      for (int j = 0; j < 8; ++j) {
        int a = xval[j] ? (xbase[nt] + xoff[j]) : OFF_B;  // OFF_B = xs[0][0][0] == 0
        bf[j] = *(const f16*)(smem + a);
      }
      #pragma unroll
      for (int mt = 0; mt < 4; ++mt)
        acc[mt][nt] = MFMA16(Ax[mt], bf, acc[mt][nt]);
    }
    __syncthreads();  // all hpad/xs reads done

    // cell update fully in-register (acc tiles mt=0..3 are gates i,f,o,g at the same (ch,n))
    #pragma unroll
    for (int nt = 0; nt < 8; ++nt) {
      f16 hh[4];
      #pragma unroll
      for (int r = 0; r < 4; ++r) {
        float ig = sigm(acc[0][nt][r]);
        float fg = sigm(acc[1][nt][r]);
        float og = sigm(acc[2][nt][r]);
        float gg = tanh_(acc[3][nt][r]);
        float cn = fg * cst[nt][r] + ig * gg;
        cst[nt][r] = cn;
        hh[r] = (f16)(og * tanh_(cn));
      }
      if (t < 11) {
        f16x4 hv = {hh[0], hh[1], hh[2], hh[3]};
        *(f16x4*)(smem + wbase[nt]) = hv;  // 4 consecutive channels -> ds_write_b64
      } else {
        // final h -> z[b][ch*16 + pos] directly
        int n = ng * 128 + nt * 16 + lr;
        int b = n >> 4, pos = n & 15;
        int ch0 = mg * 16 + lk * 4;
        #pragma unroll
        for (int r = 0; r < 4; ++r)
          *(f16*)(smem + OFF_B + b * 1088 + (ch0 + r) * 32 + pos * 2) = hh[r];
      }
    }
    if (t < 11) {
      // stage xs(t+1)
      for (int i = tid; i < 768; i += 256) {
        int b = i / 48, rem = i - b * 48;
        int pos = rem & 15;
        int ic = rem >> 4;
        int pp = (pos >> 2) * 6 + (pos & 3) + 7;
        *(f16*)(smem + OFF_B + b * 288 + pp * 8 + ic * 2) =
            (f16)gx[(size_t)(bg + b) * 576 + (t + 1) * 48 + rem];
      }
    } else {
      // hour embedding -> z[b][512 + k]
      for (int i = tid; i < 512; i += 256) {
        int b = i >> 5, k2 = i & 31;
        float h0 = ghour[bg + b];
        float a = ghb2[k2];
        #pragma unroll
        for (int ii = 0; ii < 16; ++ii) {
          float u = fmaxf(h0 * ghw1[ii] + ghb1[ii], 0.0f);
          a += u * ghw2[ii * 32 + k2];
        }
        *(f16*)(smem + OFF_B + b * 1088 + (512 + k2) * 2) = (f16)a;
      }
    }
    __syncthreads();
  }

  // ================= decoder =================
  f16* zz  = (f16*)(smem + OFF_B);       // z  [16][544]
  f16* wch = (f16*)(smem);               // weight chunk [32][N]
  f16* a1  = (f16*)(smem + 16384);       // [16][256]
  f16* a2  = (f16*)(smem + 24576);       // [16][128]
  f16* w3s = (f16*)(smem + 28672);       // [128][32]

  // layer 1: z[16][544] @ w1[544][256] -> relu -> a1
  f32x4 acc1[4];
  #pragma unroll
  for (int i = 0; i < 4; ++i) { f32x4 z = {0.f, 0.f, 0.f, 0.f}; acc1[i] = z; }
  for (int kt = 0; kt < 17; ++kt) {
    __syncthreads();
    for (int i = tid; i < 8192; i += 256) {
      int k = i >> 8, n = i & 255;
      wch[i] = (f16)gdw1[(kt * 32 + k) * 256 + n];
    }
    __syncthreads();
    f16x8 af = *(const f16x8*)((char*)zz + lr * 1088 + (kt * 32 + lk * 8) * 2);
    #pragma unroll
    for (int nt = 0; nt < 4; ++nt) {
      int n = (wv * 4 + nt) * 16 + lr;
      f16x8 bf;
      #pragma unroll
      for (int j = 0; j < 8; ++j) bf[j] = wch[(lk * 8 + j) * 256 + n];
      acc1[nt] = MFMA16(af, bf, acc1[nt]);
    }
  }
  __syncthreads();
  #pragma unroll
  for (int nt = 0; nt < 4; ++nt) {
    int n = (wv * 4 + nt) * 16 + lr;
    float bb = gdb1[n];
    #pragma unroll
    for (int r = 0; r < 4; ++r)
      a1[(lk * 4 + r) * 256 + n] = (f16)fmaxf(acc1[nt][r] + bb, 0.0f);
  }

  // layer 2: a1[16][256] @ w2[256][128] -> relu -> a2
  f32x4 acc2[2];
  #pragma unroll
  for (int i = 0; i < 2; ++i) { f32x4 z = {0.f, 0.f, 0.f, 0.f}; acc2[i] = z; }
  for (int kt = 0; kt < 8; ++kt) {
    __syncthreads();
    for (int i = tid; i < 4096; i += 256) {
      int k = i >> 7, n = i & 127;
      wch[i] = (f16)gdw2[(kt * 32 + k) * 128 + n];
    }
    __syncthreads();
    f16x8 af = *(const f16x8*)((char*)a1 + lr * 512 + (kt * 32 + lk * 8) * 2);
    #pragma unroll
    for (int nt = 0; nt < 2; ++nt) {
      int n = (wv * 2 + nt) * 16 + lr;
      f16x8 bf;
      #pragma unroll
      for (int j = 0; j < 8; ++j) bf[j] = wch[(lk * 8 + j) * 128 + n];
      acc2[nt] = MFMA16(af, bf, acc2[nt]);
    }
  }
  __syncthreads();
  #pragma unroll
  for (int nt = 0; nt < 2; ++nt) {
    int n = (wv * 2 + nt) * 16 + lr;
    float bb = gdb2[n];
    #pragma unroll
    for (int r = 0; r < 4; ++r)
      a2[(lk * 4 + r) * 128 + n] = (f16)fmaxf(acc2[nt][r] + bb, 0.0f);
  }
  __syncthreads();

  // layer 3: a2[16][128] @ w3[128][30] -> sigmoid -> out
  for (int i = tid; i < 4096; i += 256) {
    int k = i >> 5, n = i & 31;
    w3s[i] = (n < 30) ? (f16)gdw3[k * 30 + n] : (f16)0.0f;
  }
  __syncthreads();
  if (wv < 2) {
    f32x4 acc3 = {0.f, 0.f, 0.f, 0.f};
    int n = wv * 16 + lr;
    #pragma unroll
    for (int kt = 0; kt < 4; ++kt) {
      f16x8 af = *(const f16x8*)((char*)a2 + lr * 256 + (kt * 32 + lk * 8) * 2);
      f16x8 bf;
      #pragma unroll
      for (int j = 0; j < 8; ++j) bf[j] = w3s[(kt * 32 + lk * 8 + j) * 32 + n];
      acc3 = MFMA16(af, bf, acc3);
    }
    if (n < 30) {
      float bb = gdb3[n];
      #pragma unroll
      for (int r = 0; r < 4; ++r) {
        float v = sigm(acc3[r] + bb);
        gout[(size_t)(bg + lk * 4 + r) * 30 + n] = v;
      }
    }
  }
}

extern "C" void kernel_launch(void* const* d_in, const int* in_sizes, int n_in,
                              void* d_out, int out_size, void* d_ws, size_t ws_size,
                              hipStream_t stream) {
  (void)in_sizes; (void)n_in; (void)out_size; (void)d_ws; (void)ws_size;
  hwq_fused<<<2048, 256, 0, stream>>>(
      (const float*)d_in[0],  (const float*)d_in[1],  (const float*)d_in[2],
      (const float*)d_in[3],  (const float*)d_in[4],  (const float*)d_in[5],
      (const float*)d_in[6],  (const float*)d_in[7],  (const float*)d_in[8],
      (const float*)d_in[9],  (const float*)d_in[10], (const float*)d_in[11],
      (const float*)d_in[12], (const float*)d_in[13], (float*)d_out);
}

// Round 2
// 1183.686 us; speedup vs baseline: 1.3274x; 1.3274x over previous
//
#include <hip/hip_runtime.h>

typedef _Float16 f16;
typedef _Float16 f16x8 __attribute__((ext_vector_type(8)));
typedef _Float16 f16x4 __attribute__((ext_vector_type(4)));
typedef float f32x4 __attribute__((ext_vector_type(4)));

#define MFMA16(a, b, c) __builtin_amdgcn_mfma_f32_16x16x32_f16((a), (b), (c), 0, 0, 0)

__device__ __forceinline__ float sigm(float v) { return 1.0f / (1.0f + __expf(-v)); }
__device__ __forceinline__ float tanh_(float v) { return 1.0f - 2.0f / (__expf(2.0f * v) + 1.0f); }

// ======================= Kernel A: ConvLSTM recurrence =======================
// 512 threads = 8 waves; 16 samples/block. wave = mg(0..3) x ng(0..1).
// Output channels gate-interleaved: m = ch*4 + gate, so each wave's D rows
// (row = lk*4+r) give gate = r, ch = mt_g*4 + lk -> cell update in-register.
#define XSOFF 46080   // hpad: 16 samples x 36 pos x 80B; xs: 16 x 288B after

extern "C" __global__ __launch_bounds__(512, 2)
void hwq_rec(const float* __restrict__ gx, const float* __restrict__ ghour,
             const float* __restrict__ gcw, const float* __restrict__ gcb,
             const float* __restrict__ ghw1, const float* __restrict__ ghb1,
             const float* __restrict__ ghw2, const float* __restrict__ ghb2,
             f16* __restrict__ wz)
{
  __shared__ __align__(16) char smem[50688];
  const int tid = threadIdx.x;
  const int lane = tid & 63;
  const int wv = tid >> 6;
  const int mg = wv & 3;      // channel group: ch in [mg*8, mg*8+8)
  const int ng = wv >> 2;     // sample group: b in [ng*8, ng*8+8)
  const int lr = lane & 15;
  const int lk = lane >> 4;
  const int bg = blockIdx.x << 4;

  f16x8 Ah[9][2], Ax[2];
  // ---- stage & gather h-part conv weights (2 chunks of 16 channels) ----
  {
    f16* wst = (f16*)smem;   // [4 gate][16 chl][288 = ic*9+tap]
    #pragma unroll
    for (int c = 0; c < 2; ++c) {
      __syncthreads();
      for (int i = tid; i < 18432; i += 512) {
        int gc = i / 288, rem = i - gc * 288;
        int g = gc >> 4, chl = gc & 15;
        wst[i] = (f16)gcw[(g * 32 + c * 16 + chl) * 315 + 27 + rem];
      }
      __syncthreads();
      if ((mg >> 1) == c) {
        int g = lr & 3;
        #pragma unroll
        for (int mti = 0; mti < 2; ++mti) {
          int chl = ((mg * 2 + mti) * 4 + (lr >> 2)) & 15;
          #pragma unroll
          for (int tap = 0; tap < 9; ++tap) {
            f16x8 f;
            #pragma unroll
            for (int j = 0; j < 8; ++j)
              f[j] = wst[(g * 16 + chl) * 288 + (lk * 8 + j) * 9 + tap];
            Ah[tap][mti] = f;
          }
        }
      }
    }
  }
  // ---- x-part weights, k packed as tap*3+ic (27 valid -> pad 32) ----
  {
    f16* xw = (f16*)smem;    // [128 oc][27]
    __syncthreads();
    for (int i = tid; i < 3456; i += 512) {
      int oc = i / 27, rem = i - oc * 27;
      xw[i] = (f16)gcw[oc * 315 + rem];
    }
    __syncthreads();
    int g = lr & 3;
    #pragma unroll
    for (int mti = 0; mti < 2; ++mti) {
      int oc = g * 32 + (mg * 2 + mti) * 4 + (lr >> 2);
      f16x8 f;
      #pragma unroll
      for (int j = 0; j < 8; ++j) {
        int k = lk * 8 + j;
        int tap = (k * 11) >> 5;
        int ic = k - 3 * tap;
        f[j] = (k < 27) ? xw[oc * 27 + ic * 9 + tap] : (f16)0.0f;
      }
      Ax[mti] = f;
    }
    __syncthreads();
  }

  // biases: lane's 4 acc slots = gates r of channel ch
  f32x4 biasv[2];
  #pragma unroll
  for (int mti = 0; mti < 2; ++mti) {
    int ch = (mg * 2 + mti) * 4 + lk;
    f32x4 b;
    #pragma unroll
    for (int r = 0; r < 4; ++r) b[r] = gcb[r * 32 + ch];
    biasv[mti] = b;
  }

  // ---- zero hpad+xs (h0=0, borders stay 0), stage xs(t=0) ----
  {
    float* za = (float*)smem;
    for (int i = tid; i < 12672; i += 512) za[i] = 0.0f;
    __syncthreads();
    for (int i = tid; i < 768; i += 512) {
      int b = i / 48, rem = i - b * 48;
      int pos = rem & 15, ic = rem >> 4;
      int pp = (pos >> 2) * 6 + (pos & 3) + 7;
      *(f16*)(smem + XSOFF + b * 288 + pp * 8 + ic * 2) =
          (f16)gx[(size_t)(bg + b) * 576 + rem];
    }
    __syncthreads();
  }

  const int pp0 = (lr >> 2) * 6 + (lr & 3);
  const int b0 = ng * 8;
  const int ch0 = mg * 8 + lk;                       // ch for mti=0
  const int hbase = b0 * 2880 + pp0 * 80 + lk * 16;  // B-frag base
  const int wbase = b0 * 2880 + (pp0 + 7) * 80 + ch0 * 2;
  const int xbase = XSOFF + b0 * 288 + pp0 * 8;
  int xoff[8];
  #pragma unroll
  for (int j = 0; j < 8; ++j) {
    int k = lk * 8 + j;
    int tap = (k * 11) >> 5;
    int ic = k - 3 * tap;
    // invalid k -> point at xs border cell (always 0)
    xoff[j] = (k < 27) ? (((tap / 3) * 6 + (tap % 3)) * 8 + ic * 2)
                       : (XSOFF - xbase);
  }

  float cst[2][8];
  #pragma unroll
  for (int mti = 0; mti < 2; ++mti)
    #pragma unroll
    for (int nt = 0; nt < 8; ++nt) cst[mti][nt] = 0.0f;

  for (int t = 0; t < 12; ++t) {
    f32x4 acc[2][8];
    #pragma unroll
    for (int mti = 0; mti < 2; ++mti)
      #pragma unroll
      for (int nt = 0; nt < 8; ++nt) acc[mti][nt] = biasv[mti];

    #pragma unroll
    for (int tap = 0; tap < 9; ++tap) {
      const int to = ((tap / 3) * 6 + (tap % 3)) * 80;
      #pragma unroll
      for (int nt = 0; nt < 8; ++nt) {
        f16x8 bf = *(const f16x8*)(smem + hbase + nt * 2880 + to);
        acc[0][nt] = MFMA16(Ah[tap][0], bf, acc[0][nt]);
        acc[1][nt] = MFMA16(Ah[tap][1], bf, acc[1][nt]);
      }
    }
    #pragma unroll
    for (int nt = 0; nt < 8; ++nt) {
      f16x8 bf;
      #pragma unroll
      for (int j = 0; j < 8; ++j)
        bf[j] = *(const f16*)(smem + xbase + nt * 288 + xoff[j]);
      acc[0][nt] = MFMA16(Ax[0], bf, acc[0][nt]);
      acc[1][nt] = MFMA16(Ax[1], bf, acc[1][nt]);
    }
    __syncthreads();   // all hpad/xs reads done

    #pragma unroll
    for (int mti = 0; mti < 2; ++mti) {
      #pragma unroll
      for (int nt = 0; nt < 8; ++nt) {
        float ig = sigm(acc[mti][nt][0]);
        float fg = sigm(acc[mti][nt][1]);
        float og = sigm(acc[mti][nt][2]);
        float gg = tanh_(acc[mti][nt][3]);
        float cn = fg * cst[mti][nt] + ig * gg;
        cst[mti][nt] = cn;
        f16 h = (f16)(og * tanh_(cn));
        if (t < 11) {
          *(f16*)(smem + wbase + nt * 2880 + mti * 8) = h;
        } else {
          int b = b0 + nt;
          int ch = ch0 + mti * 4;
          wz[(size_t)(bg + b) * 544 + ch * 16 + lr] = h;
        }
      }
    }
    if (t < 11) {
      for (int i = tid; i < 768; i += 512) {
        int b = i / 48, rem = i - b * 48;
        int pos = rem & 15, ic = rem >> 4;
        int pp = (pos >> 2) * 6 + (pos & 3) + 7;
        *(f16*)(smem + XSOFF + b * 288 + pp * 8 + ic * 2) =
            (f16)gx[(size_t)(bg + b) * 576 + (t + 1) * 48 + rem];
      }
    } else {
      for (int i = tid; i < 512; i += 512) {
        int b = i >> 5, k2 = i & 31;
        float h0 = ghour[bg + b];
        float a = ghb2[k2];
        #pragma unroll
        for (int ii = 0; ii < 16; ++ii) {
          float u = fmaxf(h0 * ghw1[ii] + ghb1[ii], 0.0f);
          a += u * ghw2[ii * 32 + k2];
        }
        wz[(size_t)(bg + b) * 544 + 512 + k2] = (f16)a;
      }
    }
    __syncthreads();
  }
}

// ======================= prep: weight transpose fp32->f16 =======================
extern "C" __global__ void hwq_prep(const float* __restrict__ gdw1,
                                    const float* __restrict__ gdw2,
                                    const float* __restrict__ gdw3,
                                    f16* __restrict__ w1t, f16* __restrict__ w2t,
                                    f16* __restrict__ w3t)
{
  int i0 = blockIdx.x * 256 + threadIdx.x;
  int stride = gridDim.x * 256;
  for (int idx = i0; idx < 139264; idx += stride) {
    int n = idx / 544, k = idx - n * 544;
    w1t[idx] = (f16)gdw1[k * 256 + n];
  }
  for (int idx = i0; idx < 32768; idx += stride) {
    int n = idx >> 8, k = idx & 255;
    w2t[idx] = (f16)gdw2[k * 128 + n];
  }
  for (int idx = i0; idx < 4096; idx += stride) {
    int n = idx >> 7, k = idx & 127;
    w3t[idx] = (n < 30) ? (f16)gdw3[k * 30 + n] : (f16)0.0f;
  }
}

// ======================= Kernel B: decoder MLP =======================
// 256 threads = 4 waves; 64 samples/block. a1 row stride 280 f16, a2 152 f16
// (strides odd multiples of 16B -> 2-way max on b128 reads).
extern "C" __global__ __launch_bounds__(256, 2)
void hwq_dec(const f16* __restrict__ wz, const f16* __restrict__ w1t,
             const f16* __restrict__ w2t, const f16* __restrict__ w3t,
             const float* __restrict__ gdb1, const float* __restrict__ gdb2,
             const float* __restrict__ gdb3, float* __restrict__ gout)
{
  __shared__ __align__(16) char smem[55296];
  f16* a1 = (f16*)smem;               // [64][280]
  f16* a2 = (f16*)(smem + 35840);     // [64][152]
  const int tid = threadIdx.x;
  const int lane = tid & 63;
  const int wv = tid >> 6;
  const int lr = lane & 15;
  const int lk = lane >> 4;
  const int s0 = blockIdx.x << 6;

  // ---- layer 1: z[64][544] @ w1[544][256] ----
  f32x4 acc1[4][4];
  #pragma unroll
  for (int nt = 0; nt < 4; ++nt) {
    float bb = gdb1[wv * 64 + nt * 16 + lr];
    f32x4 bv = {bb, bb, bb, bb};
    #pragma unroll
    for (int mt = 0; mt < 4; ++mt) acc1[mt][nt] = bv;
  }
  for (int kt = 0; kt < 17; ++kt) {
    f16x8 af[4];
    #pragma unroll
    for (int mt = 0; mt < 4; ++mt)
      af[mt] = *(const f16x8*)(wz + (size_t)(s0 + mt * 16 + lr) * 544 + kt * 32 + lk * 8);
    #pragma unroll
    for (int nt = 0; nt < 4; ++nt) {
      f16x8 bf = *(const f16x8*)(w1t + (size_t)(wv * 64 + nt * 16 + lr) * 544 + kt * 32 + lk * 8);
      #pragma unroll
      for (int mt = 0; mt < 4; ++mt)
        acc1[mt][nt] = MFMA16(af[mt], bf, acc1[mt][nt]);
    }
  }
  #pragma unroll
  for (int mt = 0; mt < 4; ++mt)
    #pragma unroll
    for (int nt = 0; nt < 4; ++nt) {
      int n = wv * 64 + nt * 16 + lr;
      #pragma unroll
      for (int r = 0; r < 4; ++r)
        a1[(mt * 16 + lk * 4 + r) * 280 + n] = (f16)fmaxf(acc1[mt][nt][r], 0.0f);
    }
  __syncthreads();

  // ---- layer 2: a1[64][256] @ w2[256][128] ----
  f32x4 acc2[4][2];
  #pragma unroll
  for (int nt = 0; nt < 2; ++nt) {
    float bb = gdb2[wv * 32 + nt * 16 + lr];
    f32x4 bv = {bb, bb, bb, bb};
    #pragma unroll
    for (int mt = 0; mt < 4; ++mt) acc2[mt][nt] = bv;
  }
  for (int kt = 0; kt < 8; ++kt) {
    f16x8 af[4];
    #pragma unroll
    for (int mt = 0; mt < 4; ++mt)
      af[mt] = *(const f16x8*)(a1 + (mt * 16 + lr) * 280 + kt * 32 + lk * 8);
    #pragma unroll
    for (int nt = 0; nt < 2; ++nt) {
      f16x8 bf = *(const f16x8*)(w2t + (size_t)(wv * 32 + nt * 16 + lr) * 256 + kt * 32 + lk * 8);
      #pragma unroll
      for (int mt = 0; mt < 4; ++mt)
        acc2[mt][nt] = MFMA16(af[mt], bf, acc2[mt][nt]);
    }
  }
  __syncthreads();
  #pragma unroll
  for (int mt = 0; mt < 4; ++mt)
    #pragma unroll
    for (int nt = 0; nt < 2; ++nt) {
      int n = wv * 32 + nt * 16 + lr;
      #pragma unroll
      for (int r = 0; r < 4; ++r)
        a2[(mt * 16 + lk * 4 + r) * 152 + n] = (f16)fmaxf(acc2[mt][nt][r], 0.0f);
    }
  __syncthreads();

  // ---- layer 3: a2[64][128] @ w3[128][30] -> sigmoid ----
  if (wv < 2) {
    int n = wv * 16 + lr;
    float bb = (n < 30) ? gdb3[n] : 0.0f;
    f32x4 acc3[4];
    #pragma unroll
    for (int mt = 0; mt < 4; ++mt) { f32x4 bv = {bb, bb, bb, bb}; acc3[mt] = bv; }
    #pragma unroll
    for (int kt = 0; kt < 4; ++kt) {
      f16x8 bf = *(const f16x8*)(w3t + n * 128 + kt * 32 + lk * 8);
      #pragma unroll
      for (int mt = 0; mt < 4; ++mt) {
        f16x8 af = *(const f16x8*)(a2 + (mt * 16 + lr) * 152 + kt * 32 + lk * 8);
        acc3[mt] = MFMA16(af, bf, acc3[mt]);
      }
    }
    if (n < 30) {
      #pragma unroll
      for (int mt = 0; mt < 4; ++mt)
        #pragma unroll
        for (int r = 0; r < 4; ++r)
          gout[(size_t)(s0 + mt * 16 + lk * 4 + r) * 30 + n] = sigm(acc3[mt][r]);
    }
  }
}

// ======================= Fallback: round-1 monolithic kernel =======================
#define OFF_B 46080
#define SMEM_BYTES (46080 + 17408)

extern "C" __global__ __launch_bounds__(256, 1)
void hwq_fused_mono(const float* __restrict__ gx, const float* __restrict__ ghour,
               const float* __restrict__ gcw, const float* __restrict__ gcb,
               const float* __restrict__ ghw1, const float* __restrict__ ghb1,
               const float* __restrict__ ghw2, const float* __restrict__ ghb2,
               const float* __restrict__ gdw1, const float* __restrict__ gdb1,
               const float* __restrict__ gdw2, const float* __restrict__ gdb2,
               const float* __restrict__ gdw3, const float* __restrict__ gdb3,
               float* __restrict__ gout)
{
  __shared__ __align__(16) char smem[SMEM_BYTES];
  const int tid = threadIdx.x;
  const int lane = tid & 63;
  const int wv = tid >> 6;
  const int mg = wv & 1;
  const int ng = wv >> 1;
  const int lr = lane & 15;
  const int lk = lane >> 4;
  const int bg = blockIdx.x << 4;

  f16x8 Ah[9][4];
  {
    f16* wst = (f16*)(smem);
    #pragma unroll
    for (int c = 0; c < 2; ++c) {
      __syncthreads();
      for (int i = tid; i < 18432; i += 256) {
        int oc = i / 288, rem = i - oc * 288;
        wst[i] = (f16)gcw[(c * 64 + oc) * 315 + 27 + rem];
      }
      __syncthreads();
      #pragma unroll
      for (int g = 0; g < 2; ++g) {
        int ocl = g * 32 + mg * 16 + lr;
        #pragma unroll
        for (int tap = 0; tap < 9; ++tap) {
          f16x8 f;
          #pragma unroll
          for (int j = 0; j < 8; ++j)
            f[j] = wst[ocl * 288 + (lk * 8 + j) * 9 + tap];
          Ah[tap][c * 2 + g] = f;
        }
      }
    }
  }
  f16x8 Ax[4];
  {
    f16* xw = (f16*)(smem + OFF_B);
    __syncthreads();
    for (int i = tid; i < 3456; i += 256) {
      int oc = i / 27, rem = i - oc * 27;
      xw[i] = (f16)gcw[oc * 315 + rem];
    }
    __syncthreads();
    #pragma unroll
    for (int mt = 0; mt < 4; ++mt) {
      int oc = mt * 32 + mg * 16 + lr;
      f16x8 f;
      #pragma unroll
      for (int j = 0; j < 8; ++j) {
        int k = lk * 8 + j;
        int tap = (k * 11) >> 5;
        int ic = k - 3 * tap;
        f16 v = (f16)0.0f;
        if (k < 27) v = xw[oc * 27 + ic * 9 + tap];
        f[j] = v;
      }
      Ax[mt] = f;
    }
    __syncthreads();
  }

  float bias[4][4];
  #pragma unroll
  for (int mt = 0; mt < 4; ++mt)
    #pragma unroll
    for (int r = 0; r < 4; ++r)
      bias[mt][r] = gcb[mt * 32 + mg * 16 + lk * 4 + r];

  {
    float* za = (float*)smem;
    for (int i = tid; i < 11520; i += 256) za[i] = 0.0f;
    float* zb = (float*)(smem + OFF_B);
    for (int i = tid; i < 1152; i += 256) zb[i] = 0.0f;
    __syncthreads();
    for (int i = tid; i < 768; i += 256) {
      int b = i / 48, rem = i - b * 48;
      int pos = rem & 15;
      int ic = rem >> 4;
      int pp = (pos >> 2) * 6 + (pos & 3) + 7;
      *(f16*)(smem + OFF_B + b * 288 + pp * 8 + ic * 2) =
          (f16)gx[(size_t)(bg + b) * 576 + rem];
    }
    __syncthreads();
  }

  int hbase[8], xbase[8], wbase[8];
  #pragma unroll
  for (int nt = 0; nt < 8; ++nt) {
    int n = ng * 128 + nt * 16 + lr;
    int b = n >> 4, pos = n & 15;
    int pp0 = (pos >> 2) * 6 + (pos & 3);
    hbase[nt] = b * 2880 + pp0 * 80 + lk * 16;
    xbase[nt] = OFF_B + b * 288 + pp0 * 8;
    wbase[nt] = b * 2880 + (pp0 + 7) * 80 + (mg * 16 + lk * 4) * 2;
  }
  int xoff[8], xval[8];
  #pragma unroll
  for (int j = 0; j < 8; ++j) {
    int k = lk * 8 + j;
    int tap = (k * 11) >> 5;
    int ic = k - 3 * tap;
    xoff[j] = ((tap / 3) * 6 + (tap % 3)) * 8 + ic * 2;
    xval[j] = (k < 27);
  }

  const int TOFF[9] = {0, 1, 2, 6, 7, 8, 12, 13, 14};

  f32x4 cst[8];
  #pragma unroll
  for (int nt = 0; nt < 8; ++nt) { f32x4 z = {0.f, 0.f, 0.f, 0.f}; cst[nt] = z; }

  for (int t = 0; t < 12; ++t) {
    f32x4 acc[4][8];
    #pragma unroll
    for (int mt = 0; mt < 4; ++mt) {
      f32x4 bi = {bias[mt][0], bias[mt][1], bias[mt][2], bias[mt][3]};
      #pragma unroll
      for (int nt = 0; nt < 8; ++nt) acc[mt][nt] = bi;
    }
    #pragma unroll
    for (int tap = 0; tap < 9; ++tap) {
      #pragma unroll
      for (int nt = 0; nt < 8; ++nt) {
        f16x8 bf = *(const f16x8*)(smem + hbase[nt] + TOFF[tap] * 80);
        #pragma unroll
        for (int mt = 0; mt < 4; ++mt)
          acc[mt][nt] = MFMA16(Ah[tap][mt], bf, acc[mt][nt]);
      }
    }
    #pragma unroll
    for (int nt = 0; nt < 8; ++nt) {
      f16x8 bf;
      #pragma unroll
      for (int j = 0; j < 8; ++j) {
        int a = xval[j] ? (xbase[nt] + xoff[j]) : OFF_B;
        bf[j] = *(const f16*)(smem + a);
      }
      #pragma unroll
      for (int mt = 0; mt < 4; ++mt)
        acc[mt][nt] = MFMA16(Ax[mt], bf, acc[mt][nt]);
    }
    __syncthreads();

    #pragma unroll
    for (int nt = 0; nt < 8; ++nt) {
      f16 hh[4];
      #pragma unroll
      for (int r = 0; r < 4; ++r) {
        float ig = sigm(acc[0][nt][r]);
        float fg = sigm(acc[1][nt][r]);
        float og = sigm(acc[2][nt][r]);
        float gg = tanh_(acc[3][nt][r]);
        float cn = fg * cst[nt][r] + ig * gg;
        cst[nt][r] = cn;
        hh[r] = (f16)(og * tanh_(cn));
      }
      if (t < 11) {
        f16x4 hv = {hh[0], hh[1], hh[2], hh[3]};
        *(f16x4*)(smem + wbase[nt]) = hv;
      } else {
        int n = ng * 128 + nt * 16 + lr;
        int b = n >> 4, pos = n & 15;
        int ch0 = mg * 16 + lk * 4;
        #pragma unroll
        for (int r = 0; r < 4; ++r)
          *(f16*)(smem + OFF_B + b * 1088 + (ch0 + r) * 32 + pos * 2) = hh[r];
      }
    }
    if (t < 11) {
      for (int i = tid; i < 768; i += 256) {
        int b = i / 48, rem = i - b * 48;
        int pos = rem & 15;
        int ic = rem >> 4;
        int pp = (pos >> 2) * 6 + (pos & 3) + 7;
        *(f16*)(smem + OFF_B + b * 288 + pp * 8 + ic * 2) =
            (f16)gx[(size_t)(bg + b) * 576 + (t + 1) * 48 + rem];
      }
    } else {
      for (int i = tid; i < 512; i += 256) {
        int b = i >> 5, k2 = i & 31;
        float h0 = ghour[bg + b];
        float a = ghb2[k2];
        #pragma unroll
        for (int ii = 0; ii < 16; ++ii) {
          float u = fmaxf(h0 * ghw1[ii] + ghb1[ii], 0.0f);
          a += u * ghw2[ii * 32 + k2];
        }
        *(f16*)(smem + OFF_B + b * 1088 + (512 + k2) * 2) = (f16)a;
      }
    }
    __syncthreads();
  }

  f16* zz  = (f16*)(smem + OFF_B);
  f16* wch = (f16*)(smem);
  f16* a1  = (f16*)(smem + 16384);
  f16* a2  = (f16*)(smem + 24576);
  f16* w3s = (f16*)(smem + 28672);

  f32x4 acc1[4];
  #pragma unroll
  for (int i = 0; i < 4; ++i) { f32x4 z = {0.f, 0.f, 0.f, 0.f}; acc1[i] = z; }
  for (int kt = 0; kt < 17; ++kt) {
    __syncthreads();
    for (int i = tid; i < 8192; i += 256) {
      int k = i >> 8, n = i & 255;
      wch[i] = (f16)gdw1[(kt * 32 + k) * 256 + n];
    }
    __syncthreads();
    f16x8 af = *(const f16x8*)((char*)zz + lr * 1088 + (kt * 32 + lk * 8) * 2);
    #pragma unroll
    for (int nt = 0; nt < 4; ++nt) {
      int n = (wv * 4 + nt) * 16 + lr;
      f16x8 bf;
      #pragma unroll
      for (int j = 0; j < 8; ++j) bf[j] = wch[(lk * 8 + j) * 256 + n];
      acc1[nt] = MFMA16(af, bf, acc1[nt]);
    }
  }
  __syncthreads();
  #pragma unroll
  for (int nt = 0; nt < 4; ++nt) {
    int n = (wv * 4 + nt) * 16 + lr;
    float bb = gdb1[n];
    #pragma unroll
    for (int r = 0; r < 4; ++r)
      a1[(lk * 4 + r) * 256 + n] = (f16)fmaxf(acc1[nt][r] + bb, 0.0f);
  }

  f32x4 acc2[2];
  #pragma unroll
  for (int i = 0; i < 2; ++i) { f32x4 z = {0.f, 0.f, 0.f, 0.f}; acc2[i] = z; }
  for (int kt = 0; kt < 8; ++kt) {
    __syncthreads();
    for (int i = tid; i < 4096; i += 256) {
      int k = i >> 7, n = i & 127;
      wch[i] = (f16)gdw2[(kt * 32 + k) * 128 + n];
    }
    __syncthreads();
    f16x8 af = *(const f16x8*)((char*)a1 + lr * 512 + (kt * 32 + lk * 8) * 2);
    #pragma unroll
    for (int nt = 0; nt < 2; ++nt) {
      int n = (wv * 2 + nt) * 16 + lr;
      f16x8 bf;
      #pragma unroll
      for (int j = 0; j < 8; ++j) bf[j] = wch[(lk * 8 + j) * 128 + n];
      acc2[nt] = MFMA16(af, bf, acc2[nt]);
    }
  }
  __syncthreads();
  #pragma unroll
  for (int nt = 0; nt < 2; ++nt) {
    int n = (wv * 2 + nt) * 16 + lr;
    float bb = gdb2[n];
    #pragma unroll
    for (int r = 0; r < 4; ++r)
      a2[(lk * 4 + r) * 128 + n] = (f16)fmaxf(acc2[nt][r] + bb, 0.0f);
  }
  __syncthreads();

  for (int i = tid; i < 4096; i += 256) {
    int k = i >> 5, n = i & 31;
    w3s[i] = (n < 30) ? (f16)gdw3[k * 30 + n] : (f16)0.0f;
  }
  __syncthreads();
  if (wv < 2) {
    f32x4 acc3 = {0.f, 0.f, 0.f, 0.f};
    int n = wv * 16 + lr;
    #pragma unroll
    for (int kt = 0; kt < 4; ++kt) {
      f16x8 af = *(const f16x8*)((char*)a2 + lr * 256 + (kt * 32 + lk * 8) * 2);
      f16x8 bf;
      #pragma unroll
      for (int j = 0; j < 8; ++j) bf[j] = w3s[(kt * 32 + lk * 8 + j) * 32 + n];
      acc3 = MFMA16(af, bf, acc3);
    }
    if (n < 30) {
      float bb = gdb3[n];
      #pragma unroll
      for (int r = 0; r < 4; ++r) {
        float v = sigm(acc3[r] + bb);
        gout[(size_t)(bg + lk * 4 + r) * 30 + n] = v;
      }
    }
  }
}

extern "C" void kernel_launch(void* const* d_in, const int* in_sizes, int n_in,
                              void* d_out, int out_size, void* d_ws, size_t ws_size,
                              hipStream_t stream) {
  (void)in_sizes; (void)n_in; (void)out_size;
  const size_t W1OFF = 35651584;             // z: 32768*544*2
  const size_t W2OFF = W1OFF + 278528;       // w1t: 256*544*2
  const size_t W3OFF = W2OFF + 65536;        // w2t: 128*256*2
  const size_t NEED  = W3OFF + 8192;         // w3t: 32*128*2
  if (ws_size >= NEED) {
    f16* wz  = (f16*)d_ws;
    f16* w1t = (f16*)((char*)d_ws + W1OFF);
    f16* w2t = (f16*)((char*)d_ws + W2OFF);
    f16* w3t = (f16*)((char*)d_ws + W3OFF);
    hwq_prep<<<256, 256, 0, stream>>>((const float*)d_in[8], (const float*)d_in[10],
                                      (const float*)d_in[12], w1t, w2t, w3t);
    hwq_rec<<<2048, 512, 0, stream>>>(
        (const float*)d_in[0], (const float*)d_in[1], (const float*)d_in[2],
        (const float*)d_in[3], (const float*)d_in[4], (const float*)d_in[5],
        (const float*)d_in[6], (const float*)d_in[7], wz);
    hwq_dec<<<512, 256, 0, stream>>>(wz, w1t, w2t, w3t,
                                     (const float*)d_in[9], (const float*)d_in[11],
                                     (const float*)d_in[13], (float*)d_out);
  } else {
    hwq_fused_mono<<<2048, 256, 0, stream>>>(
        (const float*)d_in[0],  (const float*)d_in[1],  (const float*)d_in[2],
        (const float*)d_in[3],  (const float*)d_in[4],  (const float*)d_in[5],
        (const float*)d_in[6],  (const float*)d_in[7],  (const float*)d_in[8],
        (const float*)d_in[9],  (const float*)d_in[10], (const float*)d_in[11],
        (const float*)d_in[12], (const float*)d_in[13], (float*)d_out);
  }
}

// Round 3
// 1093.057 us; speedup vs baseline: 1.4375x; 1.0829x over previous
//
#include <hip/hip_runtime.h>

typedef _Float16 f16;
typedef _Float16 f16x8 __attribute__((ext_vector_type(8)));
typedef _Float16 f16x4 __attribute__((ext_vector_type(4)));
typedef float f32x4 __attribute__((ext_vector_type(4)));

#define MFMA16(a, b, c) __builtin_amdgcn_mfma_f32_16x16x32_f16((a), (b), (c), 0, 0, 0)

__device__ __forceinline__ float sigm(float v) { return 1.0f / (1.0f + __expf(-v)); }
__device__ __forceinline__ float tanh_(float v) { return 1.0f - 2.0f / (__expf(2.0f * v) + 1.0f); }

// ======================= Kernel A: ConvLSTM recurrence =======================
// 8 samples/block, 512 threads = 8 waves = mg(0..3) x ng(0..1).
// m = ch*4 + gate (gate-interleaved): wave mg owns m in [mg*32, mg*32+32) as two
// 16-row tiles (mti). D rows = lk*4+r -> gate = r, ch = mg*8 + mti*4 + lk.
// n = b*16 + pos, 256-wide... here 128: wave ng owns n in [ng*64, ng*64+64).
// Conv = 9 tap-GEMMs (K=32, h) + 1 im2col GEMM (K=27 x + k27=1 bias channel).
// Taps 0..4 A-frags in registers; taps 5..8 streamed from LDS (reg budget).
//
// LDS map (bytes):
//   hpad  [8 b][36 cell][32 ch f16]          0     .. 18432   (cell 64B, sample 2304B)
//   xs    [8 b][16 pos][32 k f16]            18432 .. 26624   (pos 64B, sample 1024B)
//   Wlds  [4 tp][128 m][32 k f16]            26624 .. 59392
//   dump  64B                                59392 .. 59456
#define HPAD 0
#define XSOFF 18432
#define WOFF 26624
#define DUMP 59392
#define SMEMA 59456

extern "C" __global__ __launch_bounds__(512, 4)
void hwq_rec(const float* __restrict__ gx, const float* __restrict__ ghour,
             const float* __restrict__ gcw, const float* __restrict__ gcb,
             const float* __restrict__ ghw1, const float* __restrict__ ghb1,
             const float* __restrict__ ghw2, const float* __restrict__ ghb2,
             f16* __restrict__ wz)
{
  __shared__ __align__(16) char smem[SMEMA];
  const int tid = threadIdx.x;
  const int lane = tid & 63;
  const int wv = tid >> 6;
  const int mg = wv & 3;
  const int ng = wv >> 2;
  const int lr = lane & 15;
  const int lk = lane >> 4;
  const int bg = blockIdx.x << 3;                   // 8 samples/block
  const float* gxb = gx + (size_t)bg * 576;

  // ---- stage & gather reg-tap A-frags (taps 0..4), 4 chunks of 32 m-rows ----
  f16x8 Ah[5][2];
  {
    f16* wst = (f16*)smem;   // [32 m][288 = ic*9+tap]
    #pragma unroll
    for (int c = 0; c < 4; ++c) {
      __syncthreads();
      for (int i = tid; i < 9216; i += 512) {
        int mrow = i / 288, rem = i - mrow * 288;
        int m = c * 32 + mrow;
        int oc = ((m & 3) << 5) + (m >> 2);
        wst[i] = (f16)gcw[oc * 315 + 27 + rem];
      }
      __syncthreads();
      if (mg == c) {
        #pragma unroll
        for (int mti = 0; mti < 2; ++mti)
          #pragma unroll
          for (int tap = 0; tap < 5; ++tap) {
            f16x8 f;
            #pragma unroll
            for (int j = 0; j < 8; ++j)
              f[j] = wst[(mti * 16 + lr) * 288 + (lk * 8 + j) * 9 + tap];
            Ah[tap][mti] = f;
          }
      }
    }
    __syncthreads();
  }
  // ---- stage streamed-tap weights (taps 5..8) into persistent Wlds ----
  {
    f16* wl = (f16*)(smem + WOFF);
    for (int i = tid; i < 16384; i += 512) {
      int tp = i >> 12, rem = i & 4095;
      int m = rem >> 5, k = rem & 31;
      int oc = ((m & 3) << 5) + (m >> 2);
      wl[i] = (f16)gcw[oc * 315 + 27 + k * 9 + 5 + tp];
    }
  }
  // ---- x-part weights (+bias as k=27), staged in xs region, gathered to regs ----
  f16x8 Ax[2];
  {
    f16* axs = (f16*)(smem + XSOFF);   // [128 m][32 k]
    for (int i = tid; i < 4096; i += 512) {
      int m = i >> 5, k = i & 31;
      int oc = ((m & 3) << 5) + (m >> 2);
      f16 v = (f16)0.0f;
      if (k < 27) {
        int tap = k / 3, ic = k - 3 * tap;
        v = (f16)gcw[oc * 315 + ic * 9 + tap];
      } else if (k == 27) {
        v = (f16)gcb[oc];
      }
      axs[i] = v;
    }
    __syncthreads();
    #pragma unroll
    for (int mti = 0; mti < 2; ++mti) {
      f16x8 f;
      #pragma unroll
      for (int j = 0; j < 8; ++j)
        f[j] = axs[(mg * 32 + mti * 16 + lr) * 32 + lk * 8 + j];
      Ax[mti] = f;
    }
    __syncthreads();
  }

  // ---- im2col slot table (t-invariant): packed (src_elem<<16 | dst_lds_byte) ----
  unsigned pk[7];
  #pragma unroll
  for (int s = 0; s < 7; ++s) {
    int e = tid + s * 512;
    int src = 0, dst = DUMP + ((tid & 31) << 1);
    if (e < 3456) {
      int b = e / 432, r1 = e - b * 432;
      int pos = r1 / 27, k = r1 - pos * 27;
      int tap = k / 3, ic = k - 3 * tap;
      int ky = tap / 3, kx = tap - 3 * ky;
      int py = (pos >> 2) + ky - 1, px = (pos & 3) + kx - 1;
      if (py >= 0 && py < 4 && px >= 0 && px < 4) {
        src = b * 576 + ic * 16 + py * 4 + px;
        dst = XSOFF + b * 1024 + pos * 64 + k * 2;
      }
    }
    pk[s] = ((unsigned)src << 16) | (unsigned)dst;
  }

  // ---- zero hpad + xs (+dump), set bias channel, stage xs(t=0) ----
  {
    float* za = (float*)smem;
    for (int i = tid; i < 4608; i += 512) za[i] = 0.0f;           // hpad
    float* zb = (float*)(smem + XSOFF);
    for (int i = tid; i < 2048; i += 512) zb[i] = 0.0f;           // xs
    if (tid < 16) ((float*)(smem + DUMP))[tid] = 0.0f;
    __syncthreads();
    if (tid < 128) {
      int b = tid >> 4, pos = tid & 15;
      *(f16*)(smem + XSOFF + b * 1024 + pos * 64 + 54) = (f16)1.0f;  // k=27 bias ch
    }
    #pragma unroll
    for (int s = 0; s < 7; ++s) {
      unsigned u = pk[s];
      *(f16*)(smem + (u & 0xffffu)) = (f16)gxb[u >> 16];
    }
    __syncthreads();
  }

  const int pp0 = (lr >> 2) * 6 + (lr & 3);
  const int hb = (ng * 4) * 2304 + pp0 * 64 + lk * 16;     // B-frag base (hpad)
  const int xb = XSOFF + (ng * 4) * 1024 + lr * 64 + lk * 16;
  const int wb = (ng * 4) * 2304 + (pp0 + 7) * 64 + (mg * 8 + lk) * 2;
  const int wa = WOFF + (mg * 32 + lr) * 64 + lk * 16;     // streamed A base

  float cst[2][4];
  #pragma unroll
  for (int mti = 0; mti < 2; ++mti)
    #pragma unroll
    for (int nt = 0; nt < 4; ++nt) cst[mti][nt] = 0.0f;

  for (int t = 0; t < 12; ++t) {
    f32x4 acc[2][4];
    #pragma unroll
    for (int mti = 0; mti < 2; ++mti)
      #pragma unroll
      for (int nt = 0; nt < 4; ++nt) { f32x4 z = {0.f,0.f,0.f,0.f}; acc[mti][nt] = z; }

    // streamed taps 5..8 (A from LDS)
    #pragma unroll
    for (int tp = 0; tp < 4; ++tp) {
      const int tap = 5 + tp;
      const int to = ((tap / 3) * 6 + (tap % 3)) * 64;
      f16x8 af0 = *(const f16x8*)(smem + wa + tp * 8192);
      f16x8 af1 = *(const f16x8*)(smem + wa + tp * 8192 + 1024);  // +16 m rows
      #pragma unroll
      for (int nt = 0; nt < 4; ++nt) {
        f16x8 bf = *(const f16x8*)(smem + hb + nt * 2304 + to);
        acc[0][nt] = MFMA16(af0, bf, acc[0][nt]);
        acc[1][nt] = MFMA16(af1, bf, acc[1][nt]);
      }
    }
    // register taps 0..4
    #pragma unroll
    for (int tap = 0; tap < 5; ++tap) {
      const int to = ((tap / 3) * 6 + (tap % 3)) * 64;
      #pragma unroll
      for (int nt = 0; nt < 4; ++nt) {
        f16x8 bf = *(const f16x8*)(smem + hb + nt * 2304 + to);
        acc[0][nt] = MFMA16(Ah[tap][0], bf, acc[0][nt]);
        acc[1][nt] = MFMA16(Ah[tap][1], bf, acc[1][nt]);
      }
    }
    // x + bias (im2col, clean b128 B-frags)
    #pragma unroll
    for (int nt = 0; nt < 4; ++nt) {
      f16x8 bf = *(const f16x8*)(smem + xb + nt * 1024);
      acc[0][nt] = MFMA16(Ax[0], bf, acc[0][nt]);
      acc[1][nt] = MFMA16(Ax[1], bf, acc[1][nt]);
    }
    __syncthreads();   // all hpad/xs reads done

    // cell update in-register: acc[mti][nt] = (i,f,o,g) of one channel
    #pragma unroll
    for (int mti = 0; mti < 2; ++mti) {
      #pragma unroll
      for (int nt = 0; nt < 4; ++nt) {
        float ig = sigm(acc[mti][nt][0]);
        float fg = sigm(acc[mti][nt][1]);
        float og = sigm(acc[mti][nt][2]);
        float gg = tanh_(acc[mti][nt][3]);
        float cn = fg * cst[mti][nt] + ig * gg;
        cst[mti][nt] = cn;
        f16 h = (f16)(og * tanh_(cn));
        if (t < 11) {
          *(f16*)(smem + wb + nt * 2304 + mti * 8) = h;
        } else {
          int b = ng * 4 + nt;
          int ch = mg * 8 + mti * 4 + lk;
          wz[(size_t)(bg + b) * 544 + ch * 16 + lr] = h;
        }
      }
    }
    if (t < 11) {
      const float* gxt = gxb + (t + 1) * 48;
      #pragma unroll
      for (int s = 0; s < 7; ++s) {
        unsigned u = pk[s];
        *(f16*)(smem + (u & 0xffffu)) = (f16)gxt[u >> 16];
      }
    } else if (tid < 256) {
      int b = tid >> 5, k2 = tid & 31;
      float h0 = ghour[bg + b];
      float a = ghb2[k2];
      #pragma unroll
      for (int ii = 0; ii < 16; ++ii) {
        float u = fmaxf(h0 * ghw1[ii] + ghb1[ii], 0.0f);
        a += u * ghw2[ii * 32 + k2];
      }
      wz[(size_t)(bg + b) * 544 + 512 + k2] = (f16)a;
    }
    __syncthreads();
  }
}

// ======================= prep: weight transpose fp32->f16 =======================
extern "C" __global__ void hwq_prep(const float* __restrict__ gdw1,
                                    const float* __restrict__ gdw2,
                                    const float* __restrict__ gdw3,
                                    f16* __restrict__ w1t, f16* __restrict__ w2t,
                                    f16* __restrict__ w3t)
{
  int i0 = blockIdx.x * 256 + threadIdx.x;
  int stride = gridDim.x * 256;
  for (int idx = i0; idx < 139264; idx += stride) {
    int n = idx / 544, k = idx - n * 544;
    w1t[idx] = (f16)gdw1[k * 256 + n];
  }
  for (int idx = i0; idx < 32768; idx += stride) {
    int n = idx >> 8, k = idx & 255;
    w2t[idx] = (f16)gdw2[k * 128 + n];
  }
  for (int idx = i0; idx < 4096; idx += stride) {
    int n = idx >> 7, k = idx & 127;
    w3t[idx] = (n < 30) ? (f16)gdw3[k * 30 + n] : (f16)0.0f;
  }
}

// ======================= Kernel B: decoder MLP =======================
extern "C" __global__ __launch_bounds__(256, 2)
void hwq_dec(const f16* __restrict__ wz, const f16* __restrict__ w1t,
             const f16* __restrict__ w2t, const f16* __restrict__ w3t,
             const float* __restrict__ gdb1, const float* __restrict__ gdb2,
             const float* __restrict__ gdb3, float* __restrict__ gout)
{
  __shared__ __align__(16) char smem[55296];
  f16* a1 = (f16*)smem;               // [64][280]
  f16* a2 = (f16*)(smem + 35840);     // [64][152]
  const int tid = threadIdx.x;
  const int lane = tid & 63;
  const int wv = tid >> 6;
  const int lr = lane & 15;
  const int lk = lane >> 4;
  const int s0 = blockIdx.x << 6;

  f32x4 acc1[4][4];
  #pragma unroll
  for (int nt = 0; nt < 4; ++nt) {
    float bb = gdb1[wv * 64 + nt * 16 + lr];
    f32x4 bv = {bb, bb, bb, bb};
    #pragma unroll
    for (int mt = 0; mt < 4; ++mt) acc1[mt][nt] = bv;
  }
  for (int kt = 0; kt < 17; ++kt) {
    f16x8 af[4];
    #pragma unroll
    for (int mt = 0; mt < 4; ++mt)
      af[mt] = *(const f16x8*)(wz + (size_t)(s0 + mt * 16 + lr) * 544 + kt * 32 + lk * 8);
    #pragma unroll
    for (int nt = 0; nt < 4; ++nt) {
      f16x8 bf = *(const f16x8*)(w1t + (size_t)(wv * 64 + nt * 16 + lr) * 544 + kt * 32 + lk * 8);
      #pragma unroll
      for (int mt = 0; mt < 4; ++mt)
        acc1[mt][nt] = MFMA16(af[mt], bf, acc1[mt][nt]);
    }
  }
  #pragma unroll
  for (int mt = 0; mt < 4; ++mt)
    #pragma unroll
    for (int nt = 0; nt < 4; ++nt) {
      int n = wv * 64 + nt * 16 + lr;
      #pragma unroll
      for (int r = 0; r < 4; ++r)
        a1[(mt * 16 + lk * 4 + r) * 280 + n] = (f16)fmaxf(acc1[mt][nt][r], 0.0f);
    }
  __syncthreads();

  f32x4 acc2[4][2];
  #pragma unroll
  for (int nt = 0; nt < 2; ++nt) {
    float bb = gdb2[wv * 32 + nt * 16 + lr];
    f32x4 bv = {bb, bb, bb, bb};
    #pragma unroll
    for (int mt = 0; mt < 4; ++mt) acc2[mt][nt] = bv;
  }
  for (int kt = 0; kt < 8; ++kt) {
    f16x8 af[4];
    #pragma unroll
    for (int mt = 0; mt < 4; ++mt)
      af[mt] = *(const f16x8*)(a1 + (mt * 16 + lr) * 280 + kt * 32 + lk * 8);
    #pragma unroll
    for (int nt = 0; nt < 2; ++nt) {
      f16x8 bf = *(const f16x8*)(w2t + (size_t)(wv * 32 + nt * 16 + lr) * 256 + kt * 32 + lk * 8);
      #pragma unroll
      for (int mt = 0; mt < 4; ++mt)
        acc2[mt][nt] = MFMA16(af[mt], bf, acc2[mt][nt]);
    }
  }
  __syncthreads();
  #pragma unroll
  for (int mt = 0; mt < 4; ++mt)
    #pragma unroll
    for (int nt = 0; nt < 2; ++nt) {
      int n = wv * 32 + nt * 16 + lr;
      #pragma unroll
      for (int r = 0; r < 4; ++r)
        a2[(mt * 16 + lk * 4 + r) * 152 + n] = (f16)fmaxf(acc2[mt][nt][r], 0.0f);
    }
  __syncthreads();

  if (wv < 2) {
    int n = wv * 16 + lr;
    float bb = (n < 30) ? gdb3[n] : 0.0f;
    f32x4 acc3[4];
    #pragma unroll
    for (int mt = 0; mt < 4; ++mt) { f32x4 bv = {bb, bb, bb, bb}; acc3[mt] = bv; }
    #pragma unroll
    for (int kt = 0; kt < 4; ++kt) {
      f16x8 bf = *(const f16x8*)(w3t + n * 128 + kt * 32 + lk * 8);
      #pragma unroll
      for (int mt = 0; mt < 4; ++mt) {
        f16x8 af = *(const f16x8*)(a2 + (mt * 16 + lr) * 152 + kt * 32 + lk * 8);
        acc3[mt] = MFMA16(af, bf, acc3[mt]);
      }
    }
    if (n < 30) {
      #pragma unroll
      for (int mt = 0; mt < 4; ++mt)
        #pragma unroll
        for (int r = 0; r < 4; ++r)
          gout[(size_t)(s0 + mt * 16 + lk * 4 + r) * 30 + n] = sigm(acc3[mt][r]);
    }
  }
}

// ======================= Fallback: monolithic kernel (R1) =======================
#define OFF_B 46080
#define SMEM_BYTES (46080 + 17408)

extern "C" __global__ __launch_bounds__(256, 1)
void hwq_fused_mono(const float* __restrict__ gx, const float* __restrict__ ghour,
               const float* __restrict__ gcw, const float* __restrict__ gcb,
               const float* __restrict__ ghw1, const float* __restrict__ ghb1,
               const float* __restrict__ ghw2, const float* __restrict__ ghb2,
               const float* __restrict__ gdw1, const float* __restrict__ gdb1,
               const float* __restrict__ gdw2, const float* __restrict__ gdb2,
               const float* __restrict__ gdw3, const float* __restrict__ gdb3,
               float* __restrict__ gout)
{
  __shared__ __align__(16) char smem[SMEM_BYTES];
  const int tid = threadIdx.x;
  const int lane = tid & 63;
  const int wv = tid >> 6;
  const int mg = wv & 1;
  const int ng = wv >> 1;
  const int lr = lane & 15;
  const int lk = lane >> 4;
  const int bg = blockIdx.x << 4;

  f16x8 Ah[9][4];
  {
    f16* wst = (f16*)(smem);
    #pragma unroll
    for (int c = 0; c < 2; ++c) {
      __syncthreads();
      for (int i = tid; i < 18432; i += 256) {
        int oc = i / 288, rem = i - oc * 288;
        wst[i] = (f16)gcw[(c * 64 + oc) * 315 + 27 + rem];
      }
      __syncthreads();
      #pragma unroll
      for (int g = 0; g < 2; ++g) {
        int ocl = g * 32 + mg * 16 + lr;
        #pragma unroll
        for (int tap = 0; tap < 9; ++tap) {
          f16x8 f;
          #pragma unroll
          for (int j = 0; j < 8; ++j)
            f[j] = wst[ocl * 288 + (lk * 8 + j) * 9 + tap];
          Ah[tap][c * 2 + g] = f;
        }
      }
    }
  }
  f16x8 Ax[4];
  {
    f16* xw = (f16*)(smem + OFF_B);
    __syncthreads();
    for (int i = tid; i < 3456; i += 256) {
      int oc = i / 27, rem = i - oc * 27;
      xw[i] = (f16)gcw[oc * 315 + rem];
    }
    __syncthreads();
    #pragma unroll
    for (int mt = 0; mt < 4; ++mt) {
      int oc = mt * 32 + mg * 16 + lr;
      f16x8 f;
      #pragma unroll
      for (int j = 0; j < 8; ++j) {
        int k = lk * 8 + j;
        int tap = (k * 11) >> 5;
        int ic = k - 3 * tap;
        f16 v = (f16)0.0f;
        if (k < 27) v = xw[oc * 27 + ic * 9 + tap];
        f[j] = v;
      }
      Ax[mt] = f;
    }
    __syncthreads();
  }

  float bias[4][4];
  #pragma unroll
  for (int mt = 0; mt < 4; ++mt)
    #pragma unroll
    for (int r = 0; r < 4; ++r)
      bias[mt][r] = gcb[mt * 32 + mg * 16 + lk * 4 + r];

  {
    float* za = (float*)smem;
    for (int i = tid; i < 11520; i += 256) za[i] = 0.0f;
    float* zb = (float*)(smem + OFF_B);
    for (int i = tid; i < 1152; i += 256) zb[i] = 0.0f;
    __syncthreads();
    for (int i = tid; i < 768; i += 256) {
      int b = i / 48, rem = i - b * 48;
      int pos = rem & 15;
      int ic = rem >> 4;
      int pp = (pos >> 2) * 6 + (pos & 3) + 7;
      *(f16*)(smem + OFF_B + b * 288 + pp * 8 + ic * 2) =
          (f16)gx[(size_t)(bg + b) * 576 + rem];
    }
    __syncthreads();
  }

  int hbase[8], xbase[8], wbase[8];
  #pragma unroll
  for (int nt = 0; nt < 8; ++nt) {
    int n = ng * 128 + nt * 16 + lr;
    int b = n >> 4, pos = n & 15;
    int pp0 = (pos >> 2) * 6 + (pos & 3);
    hbase[nt] = b * 2880 + pp0 * 80 + lk * 16;
    xbase[nt] = OFF_B + b * 288 + pp0 * 8;
    wbase[nt] = b * 2880 + (pp0 + 7) * 80 + (mg * 16 + lk * 4) * 2;
  }
  int xoff[8], xval[8];
  #pragma unroll
  for (int j = 0; j < 8; ++j) {
    int k = lk * 8 + j;
    int tap = (k * 11) >> 5;
    int ic = k - 3 * tap;
    xoff[j] = ((tap / 3) * 6 + (tap % 3)) * 8 + ic * 2;
    xval[j] = (k < 27);
  }

  const int TOFF[9] = {0, 1, 2, 6, 7, 8, 12, 13, 14};

  f32x4 cst[8];
  #pragma unroll
  for (int nt = 0; nt < 8; ++nt) { f32x4 z = {0.f, 0.f, 0.f, 0.f}; cst[nt] = z; }

  for (int t = 0; t < 12; ++t) {
    f32x4 acc[4][8];
    #pragma unroll
    for (int mt = 0; mt < 4; ++mt) {
      f32x4 bi = {bias[mt][0], bias[mt][1], bias[mt][2], bias[mt][3]};
      #pragma unroll
      for (int nt = 0; nt < 8; ++nt) acc[mt][nt] = bi;
    }
    #pragma unroll
    for (int tap = 0; tap < 9; ++tap) {
      #pragma unroll
      for (int nt = 0; nt < 8; ++nt) {
        f16x8 bf = *(const f16x8*)(smem + hbase[nt] + TOFF[tap] * 80);
        #pragma unroll
        for (int mt = 0; mt < 4; ++mt)
          acc[mt][nt] = MFMA16(Ah[tap][mt], bf, acc[mt][nt]);
      }
    }
    #pragma unroll
    for (int nt = 0; nt < 8; ++nt) {
      f16x8 bf;
      #pragma unroll
      for (int j = 0; j < 8; ++j) {
        int a = xval[j] ? (xbase[nt] + xoff[j]) : OFF_B;
        bf[j] = *(const f16*)(smem + a);
      }
      #pragma unroll
      for (int mt = 0; mt < 4; ++mt)
        acc[mt][nt] = MFMA16(Ax[mt], bf, acc[mt][nt]);
    }
    __syncthreads();

    #pragma unroll
    for (int nt = 0; nt < 8; ++nt) {
      f16 hh[4];
      #pragma unroll
      for (int r = 0; r < 4; ++r) {
        float ig = sigm(acc[0][nt][r]);
        float fg = sigm(acc[1][nt][r]);
        float og = sigm(acc[2][nt][r]);
        float gg = tanh_(acc[3][nt][r]);
        float cn = fg * cst[nt][r] + ig * gg;
        cst[nt][r] = cn;
        hh[r] = (f16)(og * tanh_(cn));
      }
      if (t < 11) {
        f16x4 hv = {hh[0], hh[1], hh[2], hh[3]};
        *(f16x4*)(smem + wbase[nt]) = hv;
      } else {
        int n = ng * 128 + nt * 16 + lr;
        int b = n >> 4, pos = n & 15;
        int ch0 = mg * 16 + lk * 4;
        #pragma unroll
        for (int r = 0; r < 4; ++r)
          *(f16*)(smem + OFF_B + b * 1088 + (ch0 + r) * 32 + pos * 2) = hh[r];
      }
    }
    if (t < 11) {
      for (int i = tid; i < 768; i += 256) {
        int b = i / 48, rem = i - b * 48;
        int pos = rem & 15;
        int ic = rem >> 4;
        int pp = (pos >> 2) * 6 + (pos & 3) + 7;
        *(f16*)(smem + OFF_B + b * 288 + pp * 8 + ic * 2) =
            (f16)gx[(size_t)(bg + b) * 576 + (t + 1) * 48 + rem];
      }
    } else {
      for (int i = tid; i < 512; i += 256) {
        int b = i >> 5, k2 = i & 31;
        float h0 = ghour[bg + b];
        float a = ghb2[k2];
        #pragma unroll
        for (int ii = 0; ii < 16; ++ii) {
          float u = fmaxf(h0 * ghw1[ii] + ghb1[ii], 0.0f);
          a += u * ghw2[ii * 32 + k2];
        }
        *(f16*)(smem + OFF_B + b * 1088 + (512 + k2) * 2) = (f16)a;
      }
    }
    __syncthreads();
  }

  f16* zz  = (f16*)(smem + OFF_B);
  f16* wch = (f16*)(smem);
  f16* a1  = (f16*)(smem + 16384);
  f16* a2  = (f16*)(smem + 24576);
  f16* w3s = (f16*)(smem + 28672);

  f32x4 acc1[4];
  #pragma unroll
  for (int i = 0; i < 4; ++i) { f32x4 z = {0.f, 0.f, 0.f, 0.f}; acc1[i] = z; }
  for (int kt = 0; kt < 17; ++kt) {
    __syncthreads();
    for (int i = tid; i < 8192; i += 256) {
      int k = i >> 8, n = i & 255;
      wch[i] = (f16)gdw1[(kt * 32 + k) * 256 + n];
    }
    __syncthreads();
    f16x8 af = *(const f16x8*)((char*)zz + lr * 1088 + (kt * 32 + lk * 8) * 2);
    #pragma unroll
    for (int nt = 0; nt < 4; ++nt) {
      int n = (wv * 4 + nt) * 16 + lr;
      f16x8 bf;
      #pragma unroll
      for (int j = 0; j < 8; ++j) bf[j] = wch[(lk * 8 + j) * 256 + n];
      acc1[nt] = MFMA16(af, bf, acc1[nt]);
    }
  }
  __syncthreads();
  #pragma unroll
  for (int nt = 0; nt < 4; ++nt) {
    int n = (wv * 4 + nt) * 16 + lr;
    float bb = gdb1[n];
    #pragma unroll
    for (int r = 0; r < 4; ++r)
      a1[(lk * 4 + r) * 256 + n] = (f16)fmaxf(acc1[nt][r] + bb, 0.0f);
  }

  f32x4 acc2[2];
  #pragma unroll
  for (int i = 0; i < 2; ++i) { f32x4 z = {0.f, 0.f, 0.f, 0.f}; acc2[i] = z; }
  for (int kt = 0; kt < 8; ++kt) {
    __syncthreads();
    for (int i = tid; i < 4096; i += 256) {
      int k = i >> 7, n = i & 127;
      wch[i] = (f16)gdw2[(kt * 32 + k) * 128 + n];
    }
    __syncthreads();
    f16x8 af = *(const f16x8*)((char*)a1 + lr * 512 + (kt * 32 + lk * 8) * 2);
    #pragma unroll
    for (int nt = 0; nt < 2; ++nt) {
      int n = (wv * 2 + nt) * 16 + lr;
      f16x8 bf;
      #pragma unroll
      for (int j = 0; j < 8; ++j) bf[j] = wch[(lk * 8 + j) * 128 + n];
      acc2[nt] = MFMA16(af, bf, acc2[nt]);
    }
  }
  __syncthreads();
  #pragma unroll
  for (int nt = 0; nt < 2; ++nt) {
    int n = (wv * 2 + nt) * 16 + lr;
    float bb = gdb2[n];
    #pragma unroll
    for (int r = 0; r < 4; ++r)
      a2[(lk * 4 + r) * 128 + n] = (f16)fmaxf(acc2[nt][r] + bb, 0.0f);
  }
  __syncthreads();

  for (int i = tid; i < 4096; i += 256) {
    int k = i >> 5, n = i & 31;
    w3s[i] = (n < 30) ? (f16)gdw3[k * 30 + n] : (f16)0.0f;
  }
  __syncthreads();
  if (wv < 2) {
    f32x4 acc3 = {0.f, 0.f, 0.f, 0.f};
    int n = wv * 16 + lr;
    #pragma unroll
    for (int kt = 0; kt < 4; ++kt) {
      f16x8 af = *(const f16x8*)((char*)a2 + lr * 256 + (kt * 32 + lk * 8) * 2);
      f16x8 bf;
      #pragma unroll
      for (int j = 0; j < 8; ++j) bf[j] = w3s[(kt * 32 + lk * 8 + j) * 32 + n];
      acc3 = MFMA16(af, bf, acc3);
    }
    if (n < 30) {
      float bb = gdb3[n];
      #pragma unroll
      for (int r = 0; r < 4; ++r) {
        float v = sigm(acc3[r] + bb);
        gout[(size_t)(bg + lk * 4 + r) * 30 + n] = v;
      }
    }
  }
}

extern "C" void kernel_launch(void* const* d_in, const int* in_sizes, int n_in,
                              void* d_out, int out_size, void* d_ws, size_t ws_size,
                              hipStream_t stream) {
  (void)in_sizes; (void)n_in; (void)out_size;
  const size_t W1OFF = 35651584;             // z: 32768*544*2
  const size_t W2OFF = W1OFF + 278528;       // w1t
  const size_t W3OFF = W2OFF + 65536;        // w2t
  const size_t NEED  = W3OFF + 8192;         // w3t
  if (ws_size >= NEED) {
    f16* wz  = (f16*)d_ws;
    f16* w1t = (f16*)((char*)d_ws + W1OFF);
    f16* w2t = (f16*)((char*)d_ws + W2OFF);
    f16* w3t = (f16*)((char*)d_ws + W3OFF);
    hwq_prep<<<256, 256, 0, stream>>>((const float*)d_in[8], (const float*)d_in[10],
                                      (const float*)d_in[12], w1t, w2t, w3t);
    hwq_rec<<<4096, 512, 0, stream>>>(
        (const float*)d_in[0], (const float*)d_in[1], (const float*)d_in[2],
        (const float*)d_in[3], (const float*)d_in[4], (const float*)d_in[5],
        (const float*)d_in[6], (const float*)d_in[7], wz);
    hwq_dec<<<512, 256, 0, stream>>>(wz, w1t, w2t, w3t,
                                     (const float*)d_in[9], (const float*)d_in[11],
                                     (const float*)d_in[13], (float*)d_out);
  } else {
    hwq_fused_mono<<<2048, 256, 0, stream>>>(
        (const float*)d_in[0],  (const float*)d_in[1],  (const float*)d_in[2],
        (const float*)d_in[3],  (const float*)d_in[4],  (const float*)d_in[5],
        (const float*)d_in[6],  (const float*)d_in[7],  (const float*)d_in[8],
        (const float*)d_in[9],  (const float*)d_in[10], (const float*)d_in[11],
        (const float*)d_in[12], (const float*)d_in[13], (float*)d_out);
  }
}